// Round 7
// baseline (229.814 us; speedup 1.0000x reference)
//
#include <hip/hip_runtime.h>

typedef float nfloat4 __attribute__((ext_vector_type(4)));

// ---------------- workspace layout (u32 indices) ----------------
#define WS_CANDCNT 0
#define WS_B1      1
#define WS_K2      2
#define WS_PFX     3
#define WS_K3      4
#define H1_REP     32
#define H2_REP     8
#define WS_HIST1R  16                        // [32][256]
#define WS_HIST2R  (16 + H1_REP * 256)       // [8][4096]  (= 8208)
#define WS_HIST3   (WS_HIST2R + H2_REP * 4096)   // 40976 (single copy: ~empty flush)
#define WS_ZEND    (WS_HIST3 + 4096)             // 45072
#define WS_CAND    WS_ZEND                   // candV[cap] floats, then candI[cap] u32

#define STASH 2048

// Monotone key: larger float -> larger unsigned.
__device__ __forceinline__ unsigned fkey(float f) {
  unsigned x = __float_as_uint(f);
  return x ^ ((x & 0x80000000u) ? 0xFFFFFFFFu : 0x80000000u);
}
__device__ __forceinline__ float unkey(unsigned u) {
  unsigned x = u ^ ((u & 0x80000000u) ? 0x80000000u : 0xFFFFFFFFu);
  return __uint_as_float(x);
}

// inclusive scan over 256 threads (4 waves); sh4 has >=4 slots. blockDim==256 only.
__device__ __forceinline__ unsigned block_scan_incl(unsigned v, unsigned* sh4) {
  const int t = threadIdx.x;
  unsigned p = v;
#pragma unroll
  for (int off = 1; off < 64; off <<= 1) {
    unsigned y = __shfl_up(p, off);
    if ((t & 63) >= off) p += y;
  }
  if ((t & 63) == 63) sh4[t >> 6] = p;
  __syncthreads();
  unsigned wo = 0;
  for (int w = 0; w < (t >> 6); ++w) wo += sh4[w];
  __syncthreads();
  return p + wo;
}

// k-th largest over 256-bucket hist (descending); blockDim==256.
__device__ __forceinline__ uint2 select_desc256(const unsigned* __restrict__ gh,
                                                unsigned k, unsigned* sh4, unsigned* sel2) {
  const int t = threadIdx.x;
  unsigned cnt = gh[255 - t];
  unsigned incl = block_scan_incl(cnt, sh4);
  unsigned excl = incl - cnt;
  if (excl < k && incl >= k) { sel2[0] = (unsigned)(255 - t); sel2[1] = k - excl; }
  __syncthreads();
  uint2 r; r.x = sel2[0]; r.y = sel2[1];
  __syncthreads();
  return r;
}

// k-th largest over 4096-bucket hist (descending); verified logic.
__device__ __forceinline__ uint2 select_desc4096(const unsigned* __restrict__ gh,
                                                 unsigned k, unsigned* sh4, unsigned* sel2) {
  const int t = threadIdx.x;
  unsigned loc[16]; unsigned s = 0;
  const int base = 4095 - t * 16;
#pragma unroll
  for (int j = 0; j < 16; ++j) { unsigned c = gh[base - j]; loc[j] = c; s += c; }
  unsigned incl = block_scan_incl(s, sh4);
  unsigned excl = incl - s;
  if (excl < k && incl >= k) {
    unsigned cum = excl; int j = 0;
    while (cum + loc[j] < k) { cum += loc[j]; ++j; }
    sel2[0] = (unsigned)(base - j); sel2[1] = k - cum;
  }
  __syncthreads();
  uint2 r; r.x = sel2[0]; r.y = sel2[1];
  __syncthreads();
  return r;
}

__global__ void zero_ws(unsigned* __restrict__ ws) {
  int i = blockIdx.x * blockDim.x + threadIdx.x;
  if (i < WS_ZEND) ws[i] = 0u;
}

// K1 (R7 rework): 8-bit MSB histogram via WAVE-AGGREGATED counting.
// R5/R6 data: hist1 at 51.6us with VALU 7.8%, HBM 10%, conflicts 0 -> only the
// DS-atomic pipe can be the limiter (~92 cyc per wave64 ds_atomic, ~1.4
// lanes/cyc). Fix: per element, group same-bucket lanes via 8 __ballot rounds;
// only the group leader issues ONE LDS atomic carrying popcount(mask). Active
// lanes per DS op drop 64 -> ~12 (the per-wave distinct-bucket count for
// normal data). LDS shrinks 32KB -> 1KB; tiles are contiguous (scatter's
// proven shape): 1344 blocks x 16384 floats, 4 float4/thread issued up-front.
__global__ void __launch_bounds__(1024) hist1_kernel(
    const float* __restrict__ e, const float* __restrict__ m,
    const float* __restrict__ d, unsigned* __restrict__ ws,
    int e_blks1, int m_blks1) {
  __shared__ unsigned h[256];
  const int t = threadIdx.x;
  const int bid = blockIdx.x;
  const int lane = t & 63;
  if (t < 256) h[t] = 0u;
  __syncthreads();

  const float4* in4;
  if (bid < e_blks1)                in4 = (const float4*)e + (long long)bid * 4096;
  else if (bid < e_blks1 + m_blks1) in4 = (const float4*)m + (long long)(bid - e_blks1) * 4096;
  else                              in4 = (const float4*)d + (long long)(bid - e_blks1 - m_blks1) * 4096;

  // issue all 64 B/lane before any dependent compute
  float4 f0 = in4[t];
  float4 f1 = in4[1024 + t];
  float4 f2 = in4[2048 + t];
  float4 f3 = in4[3072 + t];

  auto count1 = [&](unsigned k) {
    // lanes sharing bucket k form a group; leader adds popcount once.
    unsigned long long ms = __ballot(1);   // active mask (full tiles -> all 64)
#pragma unroll
    for (int b = 0; b < 8; ++b) {
      unsigned long long bb = __ballot((k >> b) & 1u);
      ms &= ((k >> b) & 1u) ? bb : ~bb;
    }
    if ((unsigned)__builtin_ctzll(ms) == (unsigned)lane)
      atomicAdd(&h[k], (unsigned)__builtin_popcountll(ms));
  };
  auto acc = [&](float4 f) {
    count1(fkey(f.x) >> 24);
    count1(fkey(f.y) >> 24);
    count1(fkey(f.z) >> 24);
    count1(fkey(f.w) >> 24);
  };
  acc(f0); acc(f1); acc(f2); acc(f3);

  __syncthreads();
  if (t < 256) {
    unsigned s = h[t];
    if (s) atomicAdd(&ws[WS_HIST1R + (bid & (H1_REP - 1)) * 256 + t], s);
  }
}

// K1b: reduce 32 replicas -> LDS, then select1 -> (b1, k2).
__global__ void __launch_bounds__(256) sel1_kernel(
    const int* __restrict__ maxf, unsigned* __restrict__ ws, long long n) {
  __shared__ unsigned h256[256];
  __shared__ unsigned sh4[4];
  __shared__ unsigned sel2[2];
  const int t = threadIdx.x;
  unsigned s = 0;
#pragma unroll
  for (int r = 0; r < H1_REP; ++r) s += ws[WS_HIST1R + r * 256 + t];
  h256[t] = s;
  __syncthreads();
  long long kk = (long long)maxf[0] + 1;
  if (kk > n) {
    if (t == 0) ws[WS_B1] = 0x80u;  // thresh = +0.0f path
    return;
  }
  uint2 r = select_desc256(h256, (unsigned)kk, sh4, sel2);
  if (t == 0) { ws[WS_B1] = r.x; ws[WS_K2] = r.y; }
}

// K2: near-pure stream (proven R0/R2 body, untouched).
__global__ void __launch_bounds__(1024) scatter_kernel(
    const float* __restrict__ e, const float* __restrict__ m, const float* __restrict__ d,
    float* __restrict__ out, unsigned* __restrict__ ws, unsigned cap,
    int e_blks, int m_blks) {
  const int t = threadIdx.x;
  const int bid = blockIdx.x;
  __shared__ float    sh_v[STASH];
  __shared__ unsigned sh_i[STASH];
  __shared__ unsigned sh_cnt;
  __shared__ unsigned sh_base;
  if (t == 0) sh_cnt = 0u;
  const unsigned b1 = ws[WS_B1];
  __syncthreads();
  const float4* in4;
  if (bid < e_blks)               in4 = (const float4*)e + (long long)bid * 2048;
  else if (bid < e_blks + m_blks) in4 = (const float4*)m + (long long)(bid - e_blks) * 2048;
  else                            in4 = (const float4*)d + (long long)(bid - e_blks - m_blks) * 2048;
  const int out_base_v = bid * 2048;
  nfloat4* out4 = (nfloat4*)out + out_base_v;
  float* gcV = (float*)(ws + WS_CAND);
  unsigned* gcI = ws + WS_CAND + cap;
  auto emit1 = [&](float4 f, int v) {
    unsigned kx = fkey(f.x), ky = fkey(f.y), kz = fkey(f.z), kw = fkey(f.w);
    nfloat4 o;
    o.x = ((kx >> 24) >= b1) ? f.x : 0.0f;
    o.y = ((ky >> 24) >= b1) ? f.y : 0.0f;
    o.z = ((kz >> 24) >= b1) ? f.z : 0.0f;
    o.w = ((kw >> 24) >= b1) ? f.w : 0.0f;
    __builtin_nontemporal_store(o, &out4[v]);
    unsigned ks[4] = {kx, ky, kz, kw};
    float fs[4] = {f.x, f.y, f.z, f.w};
#pragma unroll
    for (int cc = 0; cc < 4; ++cc) {
      if ((ks[cc] >> 24) == b1) {
        unsigned idx = (unsigned)(out_base_v + v) * 4u + (unsigned)cc;
        unsigned pos = atomicAdd(&sh_cnt, 1u);
        if (pos < STASH) { sh_v[pos] = fs[cc]; sh_i[pos] = idx; }
        else {  // statistically never; correct fallback
          unsigned g = atomicAdd(&ws[WS_CANDCNT], 1u);
          gcV[g] = fs[cc]; gcI[g] = idx;
        }
      }
    }
  };
  float4 f0 = in4[t];
  float4 f1 = in4[1024 + t];
  emit1(f0, t);
  emit1(f1, 1024 + t);
  __syncthreads();
  if (t == 0) {
    unsigned tot = sh_cnt < STASH ? sh_cnt : STASH;
    sh_base = tot ? atomicAdd(&ws[WS_CANDCNT], tot) : 0u;
    sh_cnt = tot;
  }
  __syncthreads();
  const unsigned tot = sh_cnt;
  const unsigned base = sh_base;
  for (unsigned i = t; i < tot; i += 1024) {
    gcV[base + i] = sh_v[i];
    gcI[base + i] = sh_i[i];
  }
}

// K3a: stage-2 12-bit histogram over candidates (128 blocks, LDS-aggregated;
// R1 lesson). FLUSH to replica (bid&7).
__global__ void __launch_bounds__(256) candhist2_kernel(
    unsigned* __restrict__ ws, unsigned cap) {
  const int t = threadIdx.x;
  __shared__ unsigned sh_hist[4096];
  for (int i = t; i < 4096; i += 256) sh_hist[i] = 0u;
  __syncthreads();
  unsigned cnt = ws[WS_CANDCNT]; if (cnt > cap) cnt = cap;
  const float* candV = (const float*)(ws + WS_CAND);
  const unsigned G = gridDim.x * 256;
  for (unsigned i = blockIdx.x * 256 + t; i < cnt; i += G) {
    unsigned u = fkey(candV[i]);
    atomicAdd(&sh_hist[(u >> 12) & 0xFFFu], 1u);
  }
  __syncthreads();
  const unsigned rep = (blockIdx.x & (H2_REP - 1)) * 4096u;
  for (int i = t; i < 4096; i += 256) {
    unsigned v = sh_hist[i];
    if (v) atomicAdd(&ws[WS_HIST2R + rep + i], v);
  }
}

// K3b: prologue sums the 8 HIST2 replicas into LDS, does ONE select -> (pfx,k3),
// publishes them; body histograms low 12 bits of pfx-matching candidates.
__global__ void __launch_bounds__(256) candhist3_kernel(
    const int* __restrict__ maxf, unsigned* __restrict__ ws, unsigned cap, long long n) {
  const int t = threadIdx.x;
  __shared__ unsigned sh_hist[4096];
  __shared__ unsigned sh4[4];
  __shared__ unsigned sel2[2];

  long long kk = (long long)maxf[0] + 1;
  unsigned pfx;
  if (kk > n) {
    pfx = 0x80u << 12;
  } else {
    for (int i = t; i < 4096; i += 256) {
      unsigned s = 0;
#pragma unroll
      for (int r = 0; r < H2_REP; ++r) s += ws[WS_HIST2R + r * 4096 + i];
      sh_hist[i] = s;
    }
    __syncthreads();
    unsigned b1 = ws[WS_B1];
    unsigned k2 = ws[WS_K2];
    uint2 r2 = select_desc4096(sh_hist, k2, sh4, sel2);
    pfx = (b1 << 12) | r2.x;
    if (blockIdx.x == 0 && t == 0) { ws[WS_PFX] = pfx; ws[WS_K3] = r2.y; }
    __syncthreads();
  }
  // (re)zero LDS hist for stage-3 accumulation
  for (int i = t; i < 4096; i += 256) sh_hist[i] = 0u;
  __syncthreads();

  unsigned cnt = ws[WS_CANDCNT]; if (cnt > cap) cnt = cap;
  const float* candV = (const float*)(ws + WS_CAND);
  const unsigned G = gridDim.x * 256;
  for (unsigned i = blockIdx.x * 256 + t; i < cnt; i += G) {
    unsigned u = fkey(candV[i]);
    if ((u >> 12) == pfx) atomicAdd(&sh_hist[u & 0xFFFu], 1u);
  }
  __syncthreads();
  // stage-3 hist is ~99% empty: if(v) keeps this flush tiny -> single copy safe.
  for (int i = t; i < 4096; i += 256) {
    unsigned v = sh_hist[i];
    if (v) atomicAdd(&ws[WS_HIST3 + i], v);
  }
}

// K4: prologue reads (pfx,k3), ONE select over HIST3 -> exact threshold; body
// zeroes provisionally-kept candidates below it.
__global__ void __launch_bounds__(256) fixup_kernel(
    float* __restrict__ out, const int* __restrict__ maxf,
    unsigned* __restrict__ ws, unsigned cap, long long n) {
  const int t = threadIdx.x;
  __shared__ unsigned sh4[4];
  __shared__ unsigned sel2[2];

  long long kk = (long long)maxf[0] + 1;
  float th;
  if (kk > n) {
    th = 0.0f;
    __syncthreads();
  } else {
    unsigned pfx = ws[WS_PFX];
    unsigned k3  = ws[WS_K3];
    uint2 r3 = select_desc4096(ws + WS_HIST3, k3, sh4, sel2);
    th = unkey((pfx << 12) | r3.x);
  }

  unsigned cnt = ws[WS_CANDCNT]; if (cnt > cap) cnt = cap;
  const float* candV = (const float*)(ws + WS_CAND);
  const unsigned* candI = ws + WS_CAND + cap;
  const unsigned G = gridDim.x * 256;
  for (unsigned i = blockIdx.x * 256 + t; i < cnt; i += G) {
    float f = candV[i];
    if (f < th) out[candI[i]] = 0.0f;
  }
}

extern "C" void kernel_launch(void* const* d_in, const int* in_sizes, int n_in,
                              void* d_out, int out_size, void* d_ws, size_t ws_size,
                              hipStream_t stream) {
  const float* e = (const float*)d_in[0];
  const float* m = (const float*)d_in[1];
  const float* d = (const float*)d_in[2];
  const int* maxf = (const int*)d_in[3];
  float* out = (float*)d_out;
  unsigned* ws = (unsigned*)d_ws;

  const long long n0 = in_sizes[0], n1 = in_sizes[1], n2 = in_sizes[2];
  const long long n = n0 + n1 + n2;

  long long capll = ((long long)(ws_size / 4) - WS_CAND) / 2;
  if (capll < 0) capll = 0;
  if (capll > n) capll = n;   // candidates (~500K) << cap in this harness
  const unsigned cap = (unsigned)capll;

  const int e_blks = (int)(n0 / 8192), m_blks = (int)(n1 / 8192);
  const int nblocks = (int)(n / 8192);      // sizes divide exactly: 2048+512+128

  const int e_blks1 = (int)(n0 / 16384), m_blks1 = (int)(n1 / 16384);
  const int nblocks1 = (int)(n / 16384);    // 1024+256+64 = 1344

  zero_ws<<<(WS_ZEND + 255) / 256, 256, 0, stream>>>(ws);
  hist1_kernel<<<nblocks1, 1024, 0, stream>>>(e, m, d, ws, e_blks1, m_blks1);
  sel1_kernel<<<1, 256, 0, stream>>>(maxf, ws, n);
  scatter_kernel<<<nblocks, 1024, 0, stream>>>(e, m, d, out, ws, cap, e_blks, m_blks);
  candhist2_kernel<<<128, 256, 0, stream>>>(ws, cap);
  candhist3_kernel<<<128, 256, 0, stream>>>(maxf, ws, cap, n);
  fixup_kernel<<<256, 256, 0, stream>>>(out, maxf, ws, cap, n);
}